// Round 15
// baseline (73.197 us; speedup 1.0000x reference)
//
#include <hip/hip_runtime.h>
#include <hip/hip_bf16.h>

using u64 = unsigned long long;

constexpr int Bb    = 4;
constexpr int Nn    = 2048;
constexpr int INDIM = 64;
constexpr int HID   = 128;      // HIDDEN == OUT_DIM == 128
constexpr int NW    = Nn / 64;  // mask words per row = 32

// ---------------- fused: [adj 128x64 tiles + in-staging norms, 512 blocks]
//                      || [projhid, 512 blocks]
struct AdjS {
    float As[32][132];          // k-major A tile (128 rows)
    float Bs[32][68];           // k-major B tile (64 rows)
    float nA[128];              // rsqrt norms, i-rows
    float nB[64];               // rsqrt norms, j-rows
    unsigned char mb[128][8];   // packed mask bytes
};

__global__ __launch_bounds__(256) void k_adjproj(
        const float* __restrict__ emb, u64* __restrict__ maskw,
        const float* __restrict__ x,   const float* __restrict__ Wp,
        const float* __restrict__ bp,  const float* __restrict__ W1,
        const float* __restrict__ a1s, const float* __restrict__ a1d,
        float* __restrict__ hh1, float* __restrict__ s1s, float* __restrict__ s1d) {
    __shared__ __align__(16) unsigned char smem[sizeof(AdjS)];
    const int t = threadIdx.x;

    if (blockIdx.x < 512) {
        // ---------------- adj: 128(i) x 64(j) tile, 4x8 acc/thread, BK=32
        AdjS& S = *reinterpret_cast<AdjS*>(smem);
        const int i0 = (blockIdx.x >> 5) * 128;
        const int j0 = (blockIdx.x & 31) * 64;
        const int tx = t & 7, ty = t >> 3;          // tx: 8 j-groups, ty: 32 i-groups
        const int sra = t >> 1, sha = (t & 1) * 16; // A staging: 2 threads/row
        const int srb = t >> 2, shb = (t & 3) * 8;  // B staging: 4 threads/row

        float acc[4][8];
        #pragma unroll
        for (int a = 0; a < 4; ++a)
            #pragma unroll
            for (int b = 0; b < 8; ++b) acc[a][b] = 0.f;

        float sqa = 0.f, sqb = 0.f;                 // per-thread partial sum-of-squares

        for (int kc = 0; kc < HID; kc += 32) {
            const float* gA = emb + (size_t)(i0 + sra) * HID + kc + sha;
            const float* gB = emb + (size_t)(j0 + srb) * HID + kc + shb;
            #pragma unroll
            for (int e = 0; e < 16; e += 4) {
                const float4 va = *reinterpret_cast<const float4*>(gA + e);
                S.As[sha + e + 0][sra] = va.x; S.As[sha + e + 1][sra] = va.y;
                S.As[sha + e + 2][sra] = va.z; S.As[sha + e + 3][sra] = va.w;
                sqa += va.x * va.x + va.y * va.y + va.z * va.z + va.w * va.w;
            }
            #pragma unroll
            for (int e = 0; e < 8; e += 4) {
                const float4 vb = *reinterpret_cast<const float4*>(gB + e);
                S.Bs[shb + e + 0][srb] = vb.x; S.Bs[shb + e + 1][srb] = vb.y;
                S.Bs[shb + e + 2][srb] = vb.z; S.Bs[shb + e + 3][srb] = vb.w;
                sqb += vb.x * vb.x + vb.y * vb.y + vb.z * vb.z + vb.w * vb.w;
            }
            __syncthreads();
            #pragma unroll 8
            for (int k = 0; k < 32; ++k) {
                float a[4], b[8];
                *reinterpret_cast<float4*>(a)     = *reinterpret_cast<const float4*>(&S.As[k][ty * 4]);
                *reinterpret_cast<float4*>(&b[0]) = *reinterpret_cast<const float4*>(&S.Bs[k][tx * 8]);
                *reinterpret_cast<float4*>(&b[4]) = *reinterpret_cast<const float4*>(&S.Bs[k][tx * 8 + 4]);
                #pragma unroll
                for (int ii = 0; ii < 4; ++ii)
                    #pragma unroll
                    for (int jj = 0; jj < 8; ++jj)
                        acc[ii][jj] += a[ii] * b[jj];
            }
            __syncthreads();
        }

        // combine staging partials -> per-row rsqrt norms (no global rs pass)
        {
            const float ta = sqa + __shfl_xor(sqa, 1, 64);      // pair: full 128 elems
            if ((t & 1) == 0) S.nA[sra] = rsqrtf(ta + 1e-12f);
            float tb = sqb + __shfl_xor(sqb, 1, 64);
            tb += __shfl_xor(tb, 2, 64);                         // quad: full 128 elems
            if ((t & 3) == 0) S.nB[srb] = rsqrtf(tb + 1e-12f);
        }
        __syncthreads();

        float rsj[8];
        #pragma unroll
        for (int jj = 0; jj < 8; ++jj) rsj[jj] = S.nB[tx * 8 + jj];
        #pragma unroll
        for (int e = 0; e < 4; ++e) {
            const float rsi = S.nA[ty * 4 + e];
            unsigned byte = 0;
            #pragma unroll
            for (int jj = 0; jj < 8; ++jj)
                if (acc[e][jj] * rsi * rsj[jj] > 0.5f) byte |= (1u << jj);
            S.mb[ty * 4 + e][tx] = (unsigned char)byte;
        }
        __syncthreads();
        if (t < 128) {
            const u64 bits = *reinterpret_cast<const u64*>(S.mb[t]);
            maskw[(size_t)(i0 + t) * NW + (blockIdx.x & 31)] = bits;
        }
    } else {
        // ---------------- projhid: 16 rows/block (two 128-thread halves x 8)
        float (*hl)[128] = reinterpret_cast<float(*)[128]>(smem);
        const int h  = t >> 7;          // half 0/1
        const int c  = t & 127;         // channel
        const int r0 = (blockIdx.x - 512) * 16 + h * 8;

        float acc[8];
        const float bias = bp[c];
        #pragma unroll
        for (int r = 0; r < 8; ++r) acc[r] = bias;
        #pragma unroll 4
        for (int k = 0; k < INDIM; ++k) {
            const float wp = Wp[k * HID + c];
            #pragma unroll
            for (int r = 0; r < 8; ++r)
                acc[r] += x[(size_t)(r0 + r) * INDIM + k] * wp;  // block-uniform -> s_load
        }
        #pragma unroll
        for (int r = 0; r < 8; ++r) hl[h * 8 + r][c] = acc[r];
        __syncthreads();

        float a2[8];
        #pragma unroll
        for (int r = 0; r < 8; ++r) a2[r] = 0.f;
        #pragma unroll 4
        for (int k = 0; k < HID; ++k) {
            const float w = W1[k * HID + c];
            #pragma unroll
            for (int r = 0; r < 8; ++r)
                a2[r] += hl[h * 8 + r][k] * w;                   // LDS broadcast
        }
        const float as = a1s[c], ad = a1d[c];
        #pragma unroll
        for (int r = 0; r < 8; ++r) {
            hh1[(size_t)(r0 + r) * HID + c] = a2[r];
            float vs = a2[r] * as;
            float vd = a2[r] * ad;
            #pragma unroll
            for (int m = 1; m < 32; m <<= 1) {
                vs += __shfl_xor(vs, m, 32);
                vd += __shfl_xor(vd, m, 32);
            }
            if ((c & 31) == 0) {
                s1s[(size_t)(r0 + r) * 4 + (c >> 5)] = vs;
                s1d[(size_t)(r0 + r) * 4 + (c >> 5)] = vd;
            }
        }
    }
}

// ------- layer 2, fully fused: for each row i, stream over edges (i,j);
// per edge recompute g[j] (nested gat1 scan + GELU), hh2[j] GEMV, s2 reduces,
// online-softmax into out[i]. Diag j=i processed first (provides s2d[i]).
// 8 rows/block, 128 threads; all syncthreads block-uniform (ballot-driven).
__global__ __launch_bounds__(128) void k_layer2(
        const float* __restrict__ hh1,
        const float* __restrict__ s1s, const float* __restrict__ s1d,
        const u64* __restrict__ maskw, const float* __restrict__ b1v,
        const float* __restrict__ W2,
        const float* __restrict__ a2s, const float* __restrict__ a2d,
        const float* __restrict__ b2v,
        float* __restrict__ out) {
    const int r0  = blockIdx.x * 8;
    const int bb  = r0 >> 11;            // batch (blocks never straddle batches)
    const int c   = threadIdx.x;         // channel 0..127
    const int l64 = c & 63;
    const int hd  = c >> 5;              // head 0..3
    __shared__ float gl[128];

    for (int r = 0; r < 8; ++r) {
        const int row  = r0 + r;
        const int iloc = row & (Nn - 1);
        const u64* mri = maskw + (size_t)iloc * NW;
        const u64 myi = (l64 < NW) ? mri[l64] : 0ULL;
        u64 nzi = __ballot(myi != 0ULL);

        float m = -INFINITY, l = 0.f, acc = 0.f;
        float s2d_i = 0.f;

        int  jloc  = iloc;               // diag first (always present: cos_ii≈1)
        bool first = true;
        u64  word  = 0;
        int  wcur  = 0;

        while (true) {
            // ---- g[jloc]: nested gat1 scan + GELU -> gl ----
            {
                const int jr = (bb << 11) + jloc;
                const u64* mrj = maskw + (size_t)jloc * NW;
                const u64 myj = (l64 < NW) ? mrj[l64] : 0ULL;
                u64 nzj = __ballot(myj != 0ULL);
                const float sd = s1d[(size_t)jr * 4 + hd];
                float m1 = -INFINITY, l1 = 0.f, a1 = 0.f;
                while (nzj) {
                    const int w = __builtin_ctzll(nzj); nzj &= nzj - 1;
                    u64 wd = __shfl(myj, w, 64);
                    while (wd) {
                        const int bit = __builtin_ctzll(wd); wd &= wd - 1;
                        const int j2 = (bb << 11) + (w << 6) + bit;
                        float e = sd + s1s[(size_t)j2 * 4 + hd];
                        e = e > 0.f ? e : 0.2f * e;
                        const float v = hh1[(size_t)j2 * HID + c];
                        const float nm = fmaxf(m1, e);
                        const float sc = __expf(m1 - nm);
                        const float p  = __expf(e - nm);
                        l1 = l1 * sc + p; a1 = a1 * sc + p * v; m1 = nm;
                    }
                }
                float o = (l1 > 0.f ? a1 / l1 : 0.f) + b1v[c];
                o = 0.5f * o * (1.f + erff(o * 0.70710678118654752f));
                __syncthreads();          // previous GEMV finished reading gl
                gl[c] = o;
                __syncthreads();
            }
            // ---- hh2[j][c] = g[j] @ W2[:,c] ----
            float val = 0.f;
            #pragma unroll 4
            for (int k = 0; k < HID; ++k)
                val += gl[k] * W2[k * HID + c];
            // ---- per-head reductions (all lanes get the head sum) ----
            float vs = val * a2s[c];
            #pragma unroll
            for (int mm = 1; mm < 32; mm <<= 1) vs += __shfl_xor(vs, mm, 32);
            if (first) {
                float vd = val * a2d[c];
                #pragma unroll
                for (int mm = 1; mm < 32; mm <<= 1) vd += __shfl_xor(vd, mm, 32);
                s2d_i = vd;
            }
            // ---- online softmax over j ----
            float e = s2d_i + vs;
            e = e > 0.f ? e : 0.2f * e;
            const float nm = fmaxf(m, e);
            const float sc = __expf(m - nm);
            const float p  = __expf(e - nm);
            l = l * sc + p; acc = acc * sc + p * val; m = nm;

            // ---- next edge (skip diag: already done) ----
            if (first) { first = false; word = 0; }
            while (word == 0) {
                if (nzi == 0) break;
                wcur = __builtin_ctzll(nzi); nzi &= nzi - 1;
                word = __shfl(myi, wcur, 64);
                if (wcur == (iloc >> 6)) word &= ~(1ULL << (iloc & 63));
            }
            if (word == 0) break;
            const int bit = __builtin_ctzll(word); word &= word - 1;
            jloc = (wcur << 6) + bit;
        }
        out[(size_t)row * HID + c] = acc / l + b2v[c];
    }
}

// ---------------------------------------------------------------- launcher
extern "C" void kernel_launch(void* const* d_in, const int* in_sizes, int n_in,
                              void* d_out, int out_size, void* d_ws, size_t ws_size,
                              hipStream_t stream) {
    // dict order: x, embedding, Wp, bp, W1, a1_src, a1_dst, b1, W2, a2_src, a2_dst, b2
    const float* x   = (const float*)d_in[0];
    const float* emb = (const float*)d_in[1];
    const float* Wp  = (const float*)d_in[2];
    const float* bp  = (const float*)d_in[3];
    const float* W1  = (const float*)d_in[4];
    const float* a1s = (const float*)d_in[5];
    const float* a1d = (const float*)d_in[6];
    const float* b1  = (const float*)d_in[7];
    const float* W2  = (const float*)d_in[8];
    const float* a2s = (const float*)d_in[9];
    const float* a2d = (const float*)d_in[10];
    const float* b2  = (const float*)d_in[11];

    // Workspace: ~4.8 MB
    char* ws = (char*)d_ws;
    u64*  maskw = (u64*)ws;   ws += (size_t)Nn * NW * 8;           // 512 KB
    float* hh1  = (float*)ws; ws += (size_t)Bb * Nn * HID * 4;     // 4 MB
    float* s1s  = (float*)ws; ws += (size_t)Bb * Nn * 4 * 4;       // 128 KB
    float* s1d  = (float*)ws; ws += (size_t)Bb * Nn * 4 * 4;       // 128 KB

    k_adjproj<<<1024, 256, 0, stream>>>(emb, maskw, x, Wp, bp, W1, a1s, a1d,
                                        hh1, s1s, s1d);
    k_layer2<<<Bb * Nn / 8, 128, 0, stream>>>(hh1, s1s, s1d, maskw, b1,
                                              W2, a2s, a2d, b2, (float*)d_out);
}

// Round 16
// 52.171 us; speedup vs baseline: 1.4030x; 1.4030x over previous
//
#include <hip/hip_runtime.h>
#include <hip/hip_bf16.h>

using u64 = unsigned long long;

constexpr int Bb    = 4;
constexpr int Nn    = 2048;
constexpr int INDIM = 64;
constexpr int HID   = 128;      // HIDDEN == OUT_DIM == 128
constexpr int NW    = Nn / 64;  // mask words per row = 32

// ---------------- fused: [adj 128x64 tiles + in-staging norms] || [projhid]
// Roles parity-interleaved across blockIdx for CU load balance.
struct AdjS {
    float As[32][132];          // k-major A tile (128 rows)
    float Bs[32][68];           // k-major B tile (64 rows)
    float nA[128];              // rsqrt norms, i-rows
    float nB[64];               // rsqrt norms, j-rows
    unsigned char mb[128][8];   // packed mask bytes
};

__global__ __launch_bounds__(256) void k_adjproj(
        const float* __restrict__ emb, u64* __restrict__ maskw,
        const float* __restrict__ x,   const float* __restrict__ Wp,
        const float* __restrict__ bp,  const float* __restrict__ W1,
        const float* __restrict__ a1s, const float* __restrict__ a1d,
        float* __restrict__ hh1, float* __restrict__ s1s, float* __restrict__ s1d) {
    __shared__ __align__(16) unsigned char smem[sizeof(AdjS)];
    const int t   = threadIdx.x;
    const int idx = blockIdx.x >> 1;      // 0..511 within role

    if ((blockIdx.x & 1) == 0) {
        // ---------------- adj: 128(i) x 64(j) tile, 4x8 acc/thread, BK=32
        AdjS& S = *reinterpret_cast<AdjS*>(smem);
        const int i0 = (idx >> 5) * 128;
        const int j0 = (idx & 31) * 64;
        const int tx = t & 7, ty = t >> 3;          // tx: 8 j-groups, ty: 32 i-groups
        const int sra = t >> 1, sha = (t & 1) * 16; // A staging: 2 threads/row
        const int srb = t >> 2, shb = (t & 3) * 8;  // B staging: 4 threads/row

        float acc[4][8];
        #pragma unroll
        for (int a = 0; a < 4; ++a)
            #pragma unroll
            for (int b = 0; b < 8; ++b) acc[a][b] = 0.f;

        float sqa = 0.f, sqb = 0.f;                 // per-thread partial sum-of-squares

        for (int kc = 0; kc < HID; kc += 32) {
            const float* gA = emb + (size_t)(i0 + sra) * HID + kc + sha;
            const float* gB = emb + (size_t)(j0 + srb) * HID + kc + shb;
            #pragma unroll
            for (int e = 0; e < 16; e += 4) {
                const float4 va = *reinterpret_cast<const float4*>(gA + e);
                S.As[sha + e + 0][sra] = va.x; S.As[sha + e + 1][sra] = va.y;
                S.As[sha + e + 2][sra] = va.z; S.As[sha + e + 3][sra] = va.w;
                sqa += va.x * va.x + va.y * va.y + va.z * va.z + va.w * va.w;
            }
            #pragma unroll
            for (int e = 0; e < 8; e += 4) {
                const float4 vb = *reinterpret_cast<const float4*>(gB + e);
                S.Bs[shb + e + 0][srb] = vb.x; S.Bs[shb + e + 1][srb] = vb.y;
                S.Bs[shb + e + 2][srb] = vb.z; S.Bs[shb + e + 3][srb] = vb.w;
                sqb += vb.x * vb.x + vb.y * vb.y + vb.z * vb.z + vb.w * vb.w;
            }
            __syncthreads();
            #pragma unroll 8
            for (int k = 0; k < 32; ++k) {
                float a[4], b[8];
                *reinterpret_cast<float4*>(a)     = *reinterpret_cast<const float4*>(&S.As[k][ty * 4]);
                *reinterpret_cast<float4*>(&b[0]) = *reinterpret_cast<const float4*>(&S.Bs[k][tx * 8]);
                *reinterpret_cast<float4*>(&b[4]) = *reinterpret_cast<const float4*>(&S.Bs[k][tx * 8 + 4]);
                #pragma unroll
                for (int ii = 0; ii < 4; ++ii)
                    #pragma unroll
                    for (int jj = 0; jj < 8; ++jj)
                        acc[ii][jj] += a[ii] * b[jj];
            }
            __syncthreads();
        }

        // combine staging partials -> per-row rsqrt norms (no global rs pass)
        {
            const float ta = sqa + __shfl_xor(sqa, 1, 64);      // pair: full 128 elems
            if ((t & 1) == 0) S.nA[sra] = rsqrtf(ta + 1e-12f);
            float tb = sqb + __shfl_xor(sqb, 1, 64);
            tb += __shfl_xor(tb, 2, 64);                         // quad: full 128 elems
            if ((t & 3) == 0) S.nB[srb] = rsqrtf(tb + 1e-12f);
        }
        __syncthreads();

        float rsj[8];
        #pragma unroll
        for (int jj = 0; jj < 8; ++jj) rsj[jj] = S.nB[tx * 8 + jj];
        #pragma unroll
        for (int e = 0; e < 4; ++e) {
            const float rsi = S.nA[ty * 4 + e];
            unsigned byte = 0;
            #pragma unroll
            for (int jj = 0; jj < 8; ++jj)
                if (acc[e][jj] * rsi * rsj[jj] > 0.5f) byte |= (1u << jj);
            S.mb[ty * 4 + e][tx] = (unsigned char)byte;
        }
        __syncthreads();
        if (t < 128) {
            const u64 bits = *reinterpret_cast<const u64*>(S.mb[t]);
            maskw[(size_t)(i0 + t) * NW + (idx & 31)] = bits;
        }
    } else {
        // ---------------- projhid: 16 rows/block (two 128-thread halves x 8)
        float (*hl)[128] = reinterpret_cast<float(*)[128]>(smem);
        const int h  = t >> 7;          // half 0/1
        const int c  = t & 127;         // channel
        const int r0 = idx * 16 + h * 8;

        float acc[8];
        const float bias = bp[c];
        #pragma unroll
        for (int r = 0; r < 8; ++r) acc[r] = bias;
        #pragma unroll 4
        for (int k = 0; k < INDIM; ++k) {
            const float wp = Wp[k * HID + c];
            #pragma unroll
            for (int r = 0; r < 8; ++r)
                acc[r] += x[(size_t)(r0 + r) * INDIM + k] * wp;  // block-uniform -> s_load
        }
        #pragma unroll
        for (int r = 0; r < 8; ++r) hl[h * 8 + r][c] = acc[r];
        __syncthreads();

        float a2[8];
        #pragma unroll
        for (int r = 0; r < 8; ++r) a2[r] = 0.f;
        #pragma unroll 4
        for (int k = 0; k < HID; ++k) {
            const float w = W1[k * HID + c];
            #pragma unroll
            for (int r = 0; r < 8; ++r)
                a2[r] += hl[h * 8 + r][k] * w;                   // LDS broadcast
        }
        const float as = a1s[c], ad = a1d[c];
        #pragma unroll
        for (int r = 0; r < 8; ++r) {
            hh1[(size_t)(r0 + r) * HID + c] = a2[r];
            float vs = a2[r] * as;
            float vd = a2[r] * ad;
            #pragma unroll
            for (int m = 1; m < 32; m <<= 1) {
                vs += __shfl_xor(vs, m, 32);
                vd += __shfl_xor(vd, m, 32);
            }
            if ((c & 31) == 0) {
                s1s[(size_t)(r0 + r) * 4 + (c >> 5)] = vs;
                s1d[(size_t)(r0 + r) * 4 + (c >> 5)] = vd;
            }
        }
    }
}

// ------- fused: gat layer1 (+GELU) fast word-scan ; hh2 = g@W2 ; s2.
// 4 rows/block (2048 blocks), 128 threads (2 waves); wave scans 2 rows.
__global__ __launch_bounds__(128) void k_gathid2(
        const float* __restrict__ hh1,
        const float* __restrict__ s1s, const float* __restrict__ s1d,
        const u64* __restrict__ maskw, const float* __restrict__ b1v,
        const float* __restrict__ W2,
        const float* __restrict__ a2s, const float* __restrict__ a2d,
        float* __restrict__ hh2,
        float* __restrict__ s2s, float* __restrict__ s2d) {
    const int r0   = blockIdx.x * 4;
    const int bb   = r0 >> 11;          // batch index
    const int t    = threadIdx.x;
    const int wv   = t >> 6;            // wave 0/1
    const int lane = t & 63;
    const int h0   = lane >> 5, h1 = 2 + h0;
    __shared__ float gl[4][128];

    #pragma unroll
    for (int rr = 0; rr < 2; ++rr) {
        const int r   = wv * 2 + rr;
        const int row = r0 + r, i = row & (Nn - 1);
        const u64* mrow = maskw + (size_t)i * NW;
        const u64 myw = (lane < NW) ? mrow[lane] : 0ULL;   // one coalesced round
        u64 nz = __ballot(myw != 0ULL);
        const float sd0 = s1d[(size_t)row * 4 + h0];
        const float sd1 = s1d[(size_t)row * 4 + h1];
        float m0 = -INFINITY, l0 = 0.f, a0 = 0.f;
        float m1 = -INFINITY, l1 = 0.f, a1 = 0.f;
        while (nz) {
            const int w = __builtin_ctzll(nz); nz &= nz - 1;
            u64 word = __shfl(myw, w, 64);
            while (word) {
                const int bit = __builtin_ctzll(word); word &= word - 1;
                const int jr = (bb << 11) + (w << 6) + bit;
                float e0 = sd0 + s1s[(size_t)jr * 4 + h0];
                e0 = e0 > 0.f ? e0 : 0.2f * e0;
                float e1 = sd1 + s1s[(size_t)jr * 4 + h1];
                e1 = e1 > 0.f ? e1 : 0.2f * e1;
                const float v0 = hh1[(size_t)jr * HID + lane];
                const float v1 = hh1[(size_t)jr * HID + 64 + lane];
                float nm = fmaxf(m0, e0);
                float sc = __expf(m0 - nm);
                float p  = __expf(e0 - nm);
                l0 = l0 * sc + p; a0 = a0 * sc + p * v0; m0 = nm;
                nm = fmaxf(m1, e1);
                sc = __expf(m1 - nm);
                p  = __expf(e1 - nm);
                l1 = l1 * sc + p; a1 = a1 * sc + p * v1; m1 = nm;
            }
        }
        float o0 = (l0 > 0.f ? a0 / l0 : 0.f) + b1v[lane];
        float o1 = (l1 > 0.f ? a1 / l1 : 0.f) + b1v[64 + lane];
        o0 = 0.5f * o0 * (1.f + erff(o0 * 0.70710678118654752f));
        o1 = 0.5f * o1 * (1.f + erff(o1 * 0.70710678118654752f));
        gl[r][lane]      = o0;
        gl[r][64 + lane] = o1;
    }
    __syncthreads();

    // GEMV: hh2 = g@W2 ; per-head s2 reductions. c = t (128 channels).
    const int c = t;
    float acc[4];
    #pragma unroll
    for (int r = 0; r < 4; ++r) acc[r] = 0.f;
    #pragma unroll 4
    for (int k = 0; k < HID; ++k) {
        const float w = W2[k * HID + c];
        #pragma unroll
        for (int r = 0; r < 4; ++r)
            acc[r] += gl[r][k] * w;                           // LDS broadcast
    }
    const float as = a2s[c], ad = a2d[c];
    #pragma unroll
    for (int r = 0; r < 4; ++r) {
        hh2[(size_t)(r0 + r) * HID + c] = acc[r];
        float vs = acc[r] * as;
        float vd = acc[r] * ad;
        #pragma unroll
        for (int m = 1; m < 32; m <<= 1) {
            vs += __shfl_xor(vs, m, 32);
            vd += __shfl_xor(vd, m, 32);
        }
        if ((c & 31) == 0) {
            s2s[(size_t)(r0 + r) * 4 + (c >> 5)] = vs;
            s2d[(size_t)(r0 + r) * 4 + (c >> 5)] = vd;
        }
    }
}

// ------------- final masked aggregation (fast word-scan), writes f32 d_out
__global__ __launch_bounds__(64) void k_gat(const float* __restrict__ hh,
                                            const float* __restrict__ ssrc,
                                            const float* __restrict__ sdst,
                                            const u64* __restrict__ maskw,
                                            const float* __restrict__ bias,
                                            float* __restrict__ out) {
    const int row  = blockIdx.x;        // b*N + i
    const int i    = row & (Nn - 1);
    const int b    = row >> 11;
    const int lane = threadIdx.x;       // channels: lane (heads 0/1), lane+64 (heads 2/3)
    const int h0   = lane >> 5;
    const int h1   = 2 + h0;
    const float sd0 = sdst[(size_t)row * 4 + h0];
    const float sd1 = sdst[(size_t)row * 4 + h1];
    const u64* mrow = maskw + (size_t)i * NW;

    const u64 myw = (lane < NW) ? mrow[lane] : 0ULL;      // one coalesced round
    u64 nz = __ballot(myw != 0ULL);

    float m0 = -INFINITY, l0 = 0.f, a0 = 0.f;
    float m1 = -INFINITY, l1 = 0.f, a1 = 0.f;

    while (nz) {
        const int w = __builtin_ctzll(nz); nz &= nz - 1;
        u64 word = __shfl(myw, w, 64);
        while (word) {
            const int bit = __builtin_ctzll(word); word &= word - 1;
            const int jr = (b << 11) + (w << 6) + bit;
            float e0 = sd0 + ssrc[(size_t)jr * 4 + h0];
            e0 = e0 > 0.f ? e0 : 0.2f * e0;
            float e1 = sd1 + ssrc[(size_t)jr * 4 + h1];
            e1 = e1 > 0.f ? e1 : 0.2f * e1;
            const float v0 = hh[(size_t)jr * HID + lane];
            const float v1 = hh[(size_t)jr * HID + 64 + lane];
            float nm = fmaxf(m0, e0);
            float sc = __expf(m0 - nm);
            float p  = __expf(e0 - nm);
            l0 = l0 * sc + p; a0 = a0 * sc + p * v0; m0 = nm;
            nm = fmaxf(m1, e1);
            sc = __expf(m1 - nm);
            p  = __expf(e1 - nm);
            l1 = l1 * sc + p; a1 = a1 * sc + p * v1; m1 = nm;
        }
    }

    out[(size_t)row * HID + lane]      = (l0 > 0.f ? a0 / l0 : 0.f) + bias[lane];
    out[(size_t)row * HID + 64 + lane] = (l1 > 0.f ? a1 / l1 : 0.f) + bias[64 + lane];
}

// ---------------------------------------------------------------- launcher
extern "C" void kernel_launch(void* const* d_in, const int* in_sizes, int n_in,
                              void* d_out, int out_size, void* d_ws, size_t ws_size,
                              hipStream_t stream) {
    // dict order: x, embedding, Wp, bp, W1, a1_src, a1_dst, b1, W2, a2_src, a2_dst, b2
    const float* x   = (const float*)d_in[0];
    const float* emb = (const float*)d_in[1];
    const float* Wp  = (const float*)d_in[2];
    const float* bp  = (const float*)d_in[3];
    const float* W1  = (const float*)d_in[4];
    const float* a1s = (const float*)d_in[5];
    const float* a1d = (const float*)d_in[6];
    const float* b1  = (const float*)d_in[7];
    const float* W2  = (const float*)d_in[8];
    const float* a2s = (const float*)d_in[9];
    const float* a2d = (const float*)d_in[10];
    const float* b2  = (const float*)d_in[11];

    // Workspace: ~9 MB
    char* ws = (char*)d_ws;
    u64*  maskw = (u64*)ws;   ws += (size_t)Nn * NW * 8;           // 512 KB
    float* hh1  = (float*)ws; ws += (size_t)Bb * Nn * HID * 4;     // 4 MB
    float* hh2  = (float*)ws; ws += (size_t)Bb * Nn * HID * 4;     // 4 MB
    float* s1s  = (float*)ws; ws += (size_t)Bb * Nn * 4 * 4;       // 128 KB
    float* s1d  = (float*)ws; ws += (size_t)Bb * Nn * 4 * 4;       // 128 KB
    float* s2s  = (float*)ws; ws += (size_t)Bb * Nn * 4 * 4;       // 128 KB
    float* s2d  = (float*)ws; ws += (size_t)Bb * Nn * 4 * 4;       // 128 KB

    k_adjproj<<<1024, 256, 0, stream>>>(emb, maskw, x, Wp, bp, W1, a1s, a1d,
                                        hh1, s1s, s1d);
    k_gathid2<<<Bb * Nn / 4, 128, 0, stream>>>(hh1, s1s, s1d, maskw, b1,
                                               W2, a2s, a2d, hh2, s2s, s2d);
    k_gat<<<Bb * Nn, 64, 0, stream>>>(hh2, s2s, s2d, maskw, b2, (float*)d_out);
}